// Round 10
// baseline (76.973 us; speedup 1.0000x reference)
//
#include <hip/hip_runtime.h>

// IAF chain encoder, fully fused: one block = 32 batch rows, all 4 flow steps
// in-LDS. Degree-sorted hidden permutation makes all three MADE masks
// k-PREFIXES -> skip structurally-zero k-chunks. Round 10:
//  * r9's distance-3 B ring was silently collapsed by the scheduler (VGPR=64
//    proves slots never stayed live; ~1000cy/chunk = raw L2/L3 latency).
//    Fix: __builtin_amdgcn_sched_barrier(0) after every slot-load group pins
//    the loads at issue distance 3 -> ~3 chunks (~400+cy) of latency cover.

typedef _Float16 f16;
typedef __attribute__((ext_vector_type(8))) _Float16 f16x8;
typedef __attribute__((ext_vector_type(4))) float f32x4;

#define NB 8192
#define ND 256
#define NH 512
#define NT 4
#define XSTR 260   // xbuf row stride (floats)

// ws layout (fp16 els), fragment-native [T][tile=32][ks<KSMAX][lane=64][8]
// (fixed tile stride = KSMAX*512 els; chunks >= true nks(tile) are ZEROS --
//  this also guarantees the 3-chunk prologue is always in-bounds)
#define W1F_OFF 0                        // KSMAX=8  : T*32*8*512  = T*NH*ND
#define W2F_OFF (NT*NH*ND)               // KSMAX=16 : T*32*16*512 = T*NH*NH
#define W3F_OFF (W2F_OFF + NT*NH*NH)     // KSMAX=16
#define WS_ELEMS (W3F_OFF + NT*NH*NH)    // 2,621,440 els = 5.24 MB

// Degree-sorted hidden permutation. deg_h[n] = 1 + n%255 over n in [0,512).
//   j<3: deg 1, orig {0,255,510}; 3<=j<6: deg 2, orig {1,256,511};
//   j>=6: deg j>>1, orig = (j&1) ? (j>>1)+254 : (j>>1)-1.
__device__ __forceinline__ int h_orig(int j) {
  if (j < 3) return j == 0 ? 0 : (j == 1 ? 255 : 510);
  if (j < 6) return j == 3 ? 1 : (j == 4 ? 256 : 511);
  int d = j >> 1;
  return (j & 1) ? (d + 254) : (d - 1);
}
__device__ __forceinline__ int h_deg(int j) {
  return (j < 3) ? 1 : (j < 6) ? 2 : (j >> 1);
}

// M1[k][j]: k <= deg(j)-1 ; M2[k][j]: deg(k) <= deg(j) ; M3[k][n]: deg(k) <= n>>1
__global__ void prep_weights(const float* __restrict__ W1,
                             const float* __restrict__ W2,
                             const float* __restrict__ W3,
                             f16* __restrict__ ws)
{
  int idx = blockIdx.x * blockDim.x + threadIdx.x;
  if (idx >= WS_ELEMS) return;
  float v;
  if (idx < W2F_OFF) {
    int t = idx >> 17, r = idx & ((1 << 17) - 1);     // 32*8*512 = 131072
    int e = r & 7, lane = (r >> 3) & 63, ks = (r >> 9) & 7, tile = r >> 12;
    int j = tile * 16 + (lane & 15);                  // sorted hidden col
    int k = ks * 32 + (lane >> 4) * 8 + e;            // raw input row
    v = (k <= h_deg(j) - 1) ? W1[t * (ND * NH) + k * NH + h_orig(j)] : 0.f;
  } else if (idx < W3F_OFF) {
    int q = idx - W2F_OFF;
    int t = q >> 18, r = q & ((1 << 18) - 1);         // 32*16*512 = 262144
    int e = r & 7, lane = (r >> 3) & 63, ks = (r >> 9) & 15, tile = r >> 13;
    int j = tile * 16 + (lane & 15);                  // sorted hidden col
    int k = ks * 32 + (lane >> 4) * 8 + e;            // sorted hidden row
    v = (h_deg(k) <= h_deg(j)) ? W2[t * (NH * NH) + h_orig(k) * NH + h_orig(j)] : 0.f;
  } else {
    int q = idx - W3F_OFF;
    int t = q >> 18, r = q & ((1 << 18) - 1);
    int e = r & 7, lane = (r >> 3) & 63, ks = (r >> 9) & 15, tile = r >> 13;
    int n = tile * 16 + (lane & 15);                  // raw output col
    int k = ks * 32 + (lane >> 4) * 8 + e;            // sorted hidden row
    v = (h_deg(k) <= (n >> 1)) ? W3[t * (NH * 2 * ND) + h_orig(k) * (2 * ND) + n] : 0.f;
  }
  ws[idx] = (f16)v;
}

// relu(acc + bias) -> fp16 LDS tile [32][512] (sorted cols), swizzled,
// row stride 1024B. Pair-stores via shfl_xor -> all-lane ds_write_b32.
__device__ __forceinline__ void epi_relu_tile(f32x4 a0, f32x4 a1,
                                              const float* __restrict__ bias_t,
                                              f16* dst, int np, int lrow, int lk8)
{
  const bool ev = (lrow & 1) == 0;
  int n = np + lrow;
  float bv = bias_t[h_orig(n)];
  #pragma unroll
  for (int j = 0; j < 4; ++j) {
    float v0 = fmaxf(a0[j] + bv, 0.f);
    float v1 = fmaxf(a1[j] + bv, 0.f);
    float p0 = __shfl_xor(v0, 1);
    float p1 = __shfl_xor(v1, 1);
    float lo = ev ? v0 : p1;
    float hi = ev ? p0 : v1;
    int m = (ev ? 0 : 16) + lk8 * 4 + j;
    int nw = n & ~1;
    unsigned int w = (unsigned int)__builtin_bit_cast(unsigned short, (f16)lo)
                   | ((unsigned int)__builtin_bit_cast(unsigned short, (f16)hi) << 16);
    int off = m * 1024 + nw * 2;
    *(unsigned int*)((char*)dst + (off ^ ((m & 7) << 4))) = w;
  }
}

#define MFMA16 __builtin_amdgcn_mfma_f32_16x16x32_f16
#define SBAR   __builtin_amdgcn_sched_barrier(0)

// load chunk cidx into named slot S (4 x 1KiB coalesced wave reads), then a
// scheduling fence so the loads CANNOT be sunk toward their uses (r9 failure:
// scheduler collapsed the dist-3 ring; VGPR=64 was the smoking gun).
#define LOAD_SLOT(S, cidx) do {                          \
    const f16* _pA = _wtA + (cidx) * 1024;               \
    const f16* _pB = _wtB + (cidx) * 1024;               \
    S##a0 = *(const f16x8*)(_pA);                        \
    S##a1 = *(const f16x8*)(_pA + 512);                  \
    S##b0 = *(const f16x8*)(_pB);                        \
    S##b1 = *(const f16x8*)(_pB + 512);                  \
    SBAR;                                                \
  } while (0)

// consume chunk cc from slot S: 4 A ds_read_b128 + 8 MFMA
#define USE_SLOT(S, srcA, SST, cc) do {                                   \
    int _kb = 128 * (cc) + lk8 * 16;                                      \
    int _r1 = 16 + lrow;                                                  \
    int _oA0 = (lrow * (SST) + _kb) ^ ((lrow & 7) << 4);                  \
    int _oA1 = (_r1 * (SST) + _kb) ^ ((_r1 & 7) << 4);                    \
    int _oB0 = (lrow * (SST) + _kb + 64) ^ ((lrow & 7) << 4);             \
    int _oB1 = (_r1 * (SST) + _kb + 64) ^ ((_r1 & 7) << 4);               \
    f16x8 _x00 = *(const f16x8*)((const char*)(srcA) + _oA0);             \
    f16x8 _x10 = *(const f16x8*)((const char*)(srcA) + _oA1);             \
    f16x8 _x01 = *(const f16x8*)((const char*)(srcA) + _oB0);             \
    f16x8 _x11 = *(const f16x8*)((const char*)(srcA) + _oB1);             \
    aA0 = MFMA16(_x00, S##a0, aA0, 0, 0, 0);                              \
    aA1 = MFMA16(_x10, S##a0, aA1, 0, 0, 0);                              \
    aB0 = MFMA16(_x00, S##b0, aB0, 0, 0, 0);                              \
    aB1 = MFMA16(_x10, S##b0, aB1, 0, 0, 0);                              \
    aA0 = MFMA16(_x01, S##a1, aA0, 0, 0, 0);                              \
    aA1 = MFMA16(_x11, S##a1, aA1, 0, 0, 0);                              \
    aB0 = MFMA16(_x01, S##b1, aB0, 0, 0, 0);                              \
    aB1 = MFMA16(_x11, S##b1, aB1, 0, 0, 0);                              \
  } while (0)

// prologue: set stream pointers, load chunks 0..2 into slots q0..q2
#define B_PROLOGUE(pA, pB) do {                          \
    _wtA = (pA); _wtB = (pB);                            \
    LOAD_SLOT(q0, 0); LOAD_SLOT(q1, 1); LOAD_SLOT(q2, 2);\
  } while (0)

#define ZERO_ACCS do { aA0 = z4; aA1 = z4; aB0 = z4; aB1 = z4; } while (0)

// dist-3 modulo-scheduled loop, 3x unrolled with uniform exits; when slot for
// chunk k is consumed it is refilled with chunk k+3 (invariant: slots hold
// chunks c..c+2). All slot indices compile-time static; loads pinned by SBAR.
#define GEMM_LOOP(srcA, SST, ncv) do {                   \
    int _c = 0;                                          \
    for (;;) {                                           \
      USE_SLOT(q0, srcA, SST, _c);                       \
      if (_c + 3 < (ncv)) LOAD_SLOT(q0, _c + 3);         \
      if (++_c == (ncv)) break;                          \
      USE_SLOT(q1, srcA, SST, _c);                       \
      if (_c + 3 < (ncv)) LOAD_SLOT(q1, _c + 3);         \
      if (++_c == (ncv)) break;                          \
      USE_SLOT(q2, srcA, SST, _c);                       \
      if (_c + 3 < (ncv)) LOAD_SLOT(q2, _c + 3);         \
      if (++_c == (ncv)) break;                          \
    }                                                    \
  } while (0)

__global__ __launch_bounds__(1024, 4) void iaf_main(
    const float* __restrict__ mean, const float* __restrict__ logv,
    const float* __restrict__ eps,
    const float* __restrict__ b1, const float* __restrict__ b2,
    const float* __restrict__ b3,
    const f16* __restrict__ ws, float* __restrict__ out)
{
  __shared__ float xbuf[32][XSTR];                // 33.3 KB fp32 master x
  __shared__ __align__(16) f16 buf0[32 * 512];    // 32 KB (A1 uses 16 KB)
  __shared__ __align__(16) f16 buf1[32 * 512];    // 32 KB

  const int tid = threadIdx.x;
  const int wid = tid >> 6;
  const int lane = tid & 63;
  const int lrow = lane & 15;    // MFMA row (A) / col (B,C)
  const int lk8 = lane >> 4;     // MFMA k-chunk / row-group
  const int row0 = blockIdx.x * 32;

  // adjacent pairing: wave w owns tiles {2w, 2w+1} (equal prefix counts).
  const int tA = 2 * wid, tB = 2 * wid + 1;
  const int npA = tA * 16, npB = tB * 16;
  const int nc1 = wid / 4 + 1;    // chunk-pairs, W1
  const int nc23 = wid / 2 + 1;   // chunk-pairs, W2/W3

  const f32x4 z4 = {0.f, 0.f, 0.f, 0.f};
  f32x4 aA0, aA1, aB0, aB1;
  const f16 *_wtA, *_wtB;
  f16x8 q0a0, q0a1, q0b0, q0b1;
  f16x8 q1a0, q1a1, q1b0, q1b1;
  f16x8 q2a0, q2a1, q2b0, q2b1;

  // per-phase weight stream bases (per-lane)
  const int o1A = tA * 4096 + lane * 8, o1B = tB * 4096 + lane * 8;   // 8ks*512
  const int o2A = tA * 8192 + lane * 8, o2B = tB * 8192 + lane * 8;   // 16ks*512

  // x0 = mean + exp(0.5*log_var)*eps
  {
    int m = tid >> 5;
    int c0 = (tid & 31) * 8;
    const int g = (row0 + m) * ND + c0;
    #pragma unroll
    for (int i = 0; i < 8; i += 4) {
      f32x4 mu = *(const f32x4*)(mean + g + i);
      f32x4 lv = *(const f32x4*)(logv + g + i);
      f32x4 ep = *(const f32x4*)(eps + g + i);
      f32x4 x;
      #pragma unroll
      for (int q = 0; q < 4; ++q) x[q] = mu[q] + __expf(0.5f * lv[q]) * ep[q];
      *(f32x4*)(&xbuf[m][c0 + i]) = x;
    }
  }

  // hoisted prologue for W1 @ t=3 (issues before the first barrier)
  B_PROLOGUE(ws + W1F_OFF + 3 * (NH * ND) + o1A,
             ws + W1F_OFF + 3 * (NH * ND) + o1B);
  __syncthreads();

  for (int t = NT - 1; t >= 0; --t) {
    // A1[m][k] = fp16(x[m][255-k]) (reversal folded in), stride 512B, swizzled
    {
      int m = tid >> 5;
      int k0 = (tid & 31) * 8;
      f32x4 lo = *(const f32x4*)(&xbuf[m][248 - k0]);
      f32x4 hi = *(const f32x4*)(&xbuf[m][252 - k0]);
      f16x8 pk;
      pk[0] = (f16)hi[3]; pk[1] = (f16)hi[2]; pk[2] = (f16)hi[1]; pk[3] = (f16)hi[0];
      pk[4] = (f16)lo[3]; pk[5] = (f16)lo[2]; pk[6] = (f16)lo[1]; pk[7] = (f16)lo[0];
      int off = m * 512 + k0 * 2;
      *(f16x8*)((char*)buf0 + (off ^ ((m & 7) << 4))) = pk;
    }
    __syncthreads();

    // h1 = relu(x_rev @ W1m + b1)   (sorted cols)
    ZERO_ACCS;
    GEMM_LOOP(buf0, 512, nc1);
    B_PROLOGUE(ws + W2F_OFF + t * (NH * NH) + o2A,          // W2 stream, hot
               ws + W2F_OFF + t * (NH * NH) + o2B);
    epi_relu_tile(aA0, aA1, b1 + t * NH, buf1, npA, lrow, lk8);
    epi_relu_tile(aB0, aB1, b1 + t * NH, buf1, npB, lrow, lk8);
    __syncthreads();

    // h2 = relu(h1 @ W2m + b2)   (sorted rows+cols)
    ZERO_ACCS;
    GEMM_LOOP(buf1, 1024, nc23);
    B_PROLOGUE(ws + W3F_OFF + t * (NH * NH) + o2A,          // W3 stream, hot
               ws + W3F_OFF + t * (NH * NH) + o2B);
    epi_relu_tile(aA0, aA1, b2 + t * NH, buf0, npA, lrow, lk8);
    epi_relu_tile(aB0, aB1, b2 + t * NH, buf0, npB, lrow, lk8);
    __syncthreads();

    // out = h2 @ W3m + b3 ;  shift = out[:,2d], log_var = out[:,2d+1]
    ZERO_ACCS;
    GEMM_LOOP(buf0, 1024, nc23);
    {
      const int tn = (t > 0) ? (t - 1) : 0;                 // W1 of next step
      B_PROLOGUE(ws + W1F_OFF + tn * (NH * ND) + o1A,
                 ws + W1F_OFF + tn * (NH * ND) + o1B);
    }
    {
      const bool ev = (lrow & 1) == 0;
      const float* b3t = b3 + t * (2 * ND);
      float xnA[2][4], xnB[2][4];
      #pragma unroll
      for (int pt = 0; pt < 2; ++pt) {
        f32x4 o_0 = pt ? aB0 : aA0;
        f32x4 o_1 = pt ? aB1 : aA1;
        float (*xn)[4] = pt ? xnB : xnA;
        int n = (pt ? npB : npA) + lrow;
        float bv = b3t[n];
        #pragma unroll
        for (int j = 0; j < 4; ++j) {
          float o0 = o_0[j] + bv;
          float o1 = o_1[j] + bv;
          float po0 = __shfl_xor(o0, 1);   // partner column (n^1) value
          float po1 = __shfl_xor(o1, 1);
          if (ev) {                         // even col: o=shift, po=pre-tanh lv
            int d = n >> 1;
            float xc0 = xbuf[lk8 * 4 + j][255 - d];
            float e0 = __expf(2.f * po0);
            float t0 = 1.f - 2.f / (e0 + 1.f);          // tanh(po0)
            xn[0][j] = (xc0 - o0) * __expf(-t0);
            float xc1 = xbuf[16 + lk8 * 4 + j][255 - d];
            float e1 = __expf(2.f * po1);
            float t1 = 1.f - 2.f / (e1 + 1.f);
            xn[1][j] = (xc1 - o1) * __expf(-t1);
          }
        }
      }
      __syncthreads();                      // all xbuf reads done
      if (ev) {
        int dA = (npA + lrow) >> 1;
        int dB = (npB + lrow) >> 1;
        #pragma unroll
        for (int j = 0; j < 4; ++j) {
          xbuf[lk8 * 4 + j][dA]      = xnA[0][j];
          xbuf[16 + lk8 * 4 + j][dA] = xnA[1][j];
          xbuf[lk8 * 4 + j][dB]      = xnB[0][j];
          xbuf[16 + lk8 * 4 + j][dB] = xnB[1][j];
        }
      }
      __syncthreads();
    }
  }

  // store final x (fp32)
  {
    int m = tid >> 5;
    int c0 = (tid & 31) * 8;
    float* op = out + (row0 + m) * ND + c0;
    #pragma unroll
    for (int i = 0; i < 8; i += 4)
      *(f32x4*)(op + i) = *(const f32x4*)(&xbuf[m][c0 + i]);
  }
}

extern "C" void kernel_launch(void* const* d_in, const int* in_sizes, int n_in,
                              void* d_out, int out_size, void* d_ws, size_t ws_size,
                              hipStream_t stream) {
  const float* mean = (const float*)d_in[0];
  const float* logv = (const float*)d_in[1];
  const float* eps  = (const float*)d_in[2];
  const float* W1   = (const float*)d_in[3];
  const float* b1   = (const float*)d_in[4];
  const float* W2   = (const float*)d_in[5];
  const float* b2   = (const float*)d_in[6];
  const float* W3   = (const float*)d_in[7];
  const float* b3   = (const float*)d_in[8];
  f16* ws = (f16*)d_ws;   // needs 5.25 MB

  prep_weights<<<(WS_ELEMS + 255) / 256, 256, 0, stream>>>(W1, W2, W3, ws);
  iaf_main<<<NB / 32, 1024, 0, stream>>>(mean, logv, eps, b1, b2, b3, ws,
                                         (float*)d_out);
}

// Round 11
// 74.837 us; speedup vs baseline: 1.0285x; 1.0285x over previous
//
#include <hip/hip_runtime.h>

// IAF chain encoder, fully fused: one block = 32 batch rows, all 4 flow steps
// in-LDS. Degree-sorted hidden permutation makes all three MADE masks
// k-PREFIXES -> skip structurally-zero k-chunks. Round 11:
//  r9/r10 pipelines were collapsed by RA rematerialization (invariant loads
//  re-executed at use; VGPR=64 = acc+slots exactly). Fix: ALL B/bias loads are
//  volatile inline-asm global_load_* (non-remat), manual counted
//  s_waitcnt vmcnt{8,4,0} + sched_barrier(0) (T4 + rule #18). Compiler sees
//  no vmem in the hot loop -> __syncthreads no longer drains the prefetch.

typedef _Float16 f16;
typedef __attribute__((ext_vector_type(8))) _Float16 f16x8;
typedef __attribute__((ext_vector_type(4))) float f32x4;

#define NB 8192
#define ND 256
#define NH 512
#define NT 4
#define XSTR 260   // xbuf row stride (floats)

// ws layout (fp16 els), fragment-native [T][tile=32][ks<KSMAX][lane=64][8]
// (fixed tile stride = KSMAX*512 els; chunks >= true nks(tile) are ZEROS --
//  guarantees the 3-chunk prologue is always in-bounds)
#define W1F_OFF 0                        // KSMAX=8  : T*32*8*512  = T*NH*ND
#define W2F_OFF (NT*NH*ND)               // KSMAX=16 : T*32*16*512 = T*NH*NH
#define W3F_OFF (W2F_OFF + NT*NH*NH)     // KSMAX=16
#define WS_ELEMS (W3F_OFF + NT*NH*NH)    // 2,621,440 els = 5.24 MB

// Degree-sorted hidden permutation. deg_h[n] = 1 + n%255 over n in [0,512).
//   j<3: deg 1, orig {0,255,510}; 3<=j<6: deg 2, orig {1,256,511};
//   j>=6: deg j>>1, orig = (j&1) ? (j>>1)+254 : (j>>1)-1.
__device__ __forceinline__ int h_orig(int j) {
  if (j < 3) return j == 0 ? 0 : (j == 1 ? 255 : 510);
  if (j < 6) return j == 3 ? 1 : (j == 4 ? 256 : 511);
  int d = j >> 1;
  return (j & 1) ? (d + 254) : (d - 1);
}
__device__ __forceinline__ int h_deg(int j) {
  return (j < 3) ? 1 : (j < 6) ? 2 : (j >> 1);
}

// M1[k][j]: k <= deg(j)-1 ; M2[k][j]: deg(k) <= deg(j) ; M3[k][n]: deg(k) <= n>>1
__global__ void prep_weights(const float* __restrict__ W1,
                             const float* __restrict__ W2,
                             const float* __restrict__ W3,
                             f16* __restrict__ ws)
{
  int idx = blockIdx.x * blockDim.x + threadIdx.x;
  if (idx >= WS_ELEMS) return;
  float v;
  if (idx < W2F_OFF) {
    int t = idx >> 17, r = idx & ((1 << 17) - 1);     // 32*8*512 = 131072
    int e = r & 7, lane = (r >> 3) & 63, ks = (r >> 9) & 7, tile = r >> 12;
    int j = tile * 16 + (lane & 15);                  // sorted hidden col
    int k = ks * 32 + (lane >> 4) * 8 + e;            // raw input row
    v = (k <= h_deg(j) - 1) ? W1[t * (ND * NH) + k * NH + h_orig(j)] : 0.f;
  } else if (idx < W3F_OFF) {
    int q = idx - W2F_OFF;
    int t = q >> 18, r = q & ((1 << 18) - 1);         // 32*16*512 = 262144
    int e = r & 7, lane = (r >> 3) & 63, ks = (r >> 9) & 15, tile = r >> 13;
    int j = tile * 16 + (lane & 15);                  // sorted hidden col
    int k = ks * 32 + (lane >> 4) * 8 + e;            // sorted hidden row
    v = (h_deg(k) <= h_deg(j)) ? W2[t * (NH * NH) + h_orig(k) * NH + h_orig(j)] : 0.f;
  } else {
    int q = idx - W3F_OFF;
    int t = q >> 18, r = q & ((1 << 18) - 1);
    int e = r & 7, lane = (r >> 3) & 63, ks = (r >> 9) & 15, tile = r >> 13;
    int n = tile * 16 + (lane & 15);                  // raw output col
    int k = ks * 32 + (lane >> 4) * 8 + e;            // sorted hidden row
    v = (h_deg(k) <= (n >> 1)) ? W3[t * (NH * 2 * ND) + h_orig(k) * (2 * ND) + n] : 0.f;
  }
  ws[idx] = (f16)v;
}

// relu(acc + bias) -> fp16 LDS tile [32][512] (sorted cols), swizzled,
// row stride 1024B. Pair-stores via shfl_xor -> all-lane ds_write_b32.
// bv = preloaded bias value (asm-loaded register).
__device__ __forceinline__ void epi_relu_tile(f32x4 a0, f32x4 a1, float bv,
                                              f16* dst, int np, int lrow, int lk8)
{
  const bool ev = (lrow & 1) == 0;
  int n = np + lrow;
  #pragma unroll
  for (int j = 0; j < 4; ++j) {
    float v0 = fmaxf(a0[j] + bv, 0.f);
    float v1 = fmaxf(a1[j] + bv, 0.f);
    float p0 = __shfl_xor(v0, 1);
    float p1 = __shfl_xor(v1, 1);
    float lo = ev ? v0 : p1;
    float hi = ev ? p0 : v1;
    int m = (ev ? 0 : 16) + lk8 * 4 + j;
    int nw = n & ~1;
    unsigned int w = (unsigned int)__builtin_bit_cast(unsigned short, (f16)lo)
                   | ((unsigned int)__builtin_bit_cast(unsigned short, (f16)hi) << 16);
    int off = m * 1024 + nw * 2;
    *(unsigned int*)((char*)dst + (off ^ ((m & 7) << 4))) = w;
  }
}

#define MFMA16 __builtin_amdgcn_mfma_f32_16x16x32_f16

// volatile asm loads: non-rematerializable, ordered among themselves.
#define GLOADX4(dst, ptr) \
  asm volatile("global_load_dwordx4 %0, %1, off" : "=v"(dst) : "v"(ptr))
#define GLOADW(dst, ptr) \
  asm volatile("global_load_dword %0, %1, off" : "=v"(dst) : "v"(ptr))

// counted wait + scheduling fence (rule #18: fence stops MFMA hoisting)
#define WAITV(n) do { asm volatile("s_waitcnt vmcnt(" #n ")"); \
                      __builtin_amdgcn_sched_barrier(0); } while (0)
// before consuming chunk c: newer load-groups = min(2, nc-1-c) -> N=4*that.
// (under-estimates over-wait -> always safe; vmem retires in order)
#define WAITSEL(cc, ncv) do {                        \
    if ((cc) + 2 < (ncv))      WAITV(8);             \
    else if ((cc) + 1 < (ncv)) WAITV(4);             \
    else                       WAITV(0);             \
  } while (0)

// load chunk cidx into named slot S (4 x 1KiB coalesced wave reads)
#define LOAD_SLOT(S, cidx) do {                      \
    const f16* _pA = _wtA + (cidx) * 1024;           \
    const f16* _pB = _wtB + (cidx) * 1024;           \
    GLOADX4(S##a0, _pA);                             \
    GLOADX4(S##a1, (_pA + 512));                     \
    GLOADX4(S##b0, _pB);                             \
    GLOADX4(S##b1, (_pB + 512));                     \
  } while (0)

// consume chunk cc from slot S: 4 A ds_read_b128 + 8 MFMA (compiler-managed)
#define USE_SLOT(S, srcA, SST, cc) do {                                   \
    int _kb = 128 * (cc) + lk8 * 16;                                      \
    int _r1 = 16 + lrow;                                                  \
    int _oA0 = (lrow * (SST) + _kb) ^ ((lrow & 7) << 4);                  \
    int _oA1 = (_r1 * (SST) + _kb) ^ ((_r1 & 7) << 4);                    \
    int _oB0 = (lrow * (SST) + _kb + 64) ^ ((lrow & 7) << 4);             \
    int _oB1 = (_r1 * (SST) + _kb + 64) ^ ((_r1 & 7) << 4);               \
    f16x8 _x00 = *(const f16x8*)((const char*)(srcA) + _oA0);             \
    f16x8 _x10 = *(const f16x8*)((const char*)(srcA) + _oA1);             \
    f16x8 _x01 = *(const f16x8*)((const char*)(srcA) + _oB0);             \
    f16x8 _x11 = *(const f16x8*)((const char*)(srcA) + _oB1);             \
    aA0 = MFMA16(_x00, S##a0, aA0, 0, 0, 0);                              \
    aA1 = MFMA16(_x10, S##a0, aA1, 0, 0, 0);                              \
    aB0 = MFMA16(_x00, S##b0, aB0, 0, 0, 0);                              \
    aB1 = MFMA16(_x10, S##b0, aB1, 0, 0, 0);                              \
    aA0 = MFMA16(_x01, S##a1, aA0, 0, 0, 0);                              \
    aA1 = MFMA16(_x11, S##a1, aA1, 0, 0, 0);                              \
    aB0 = MFMA16(_x01, S##b1, aB0, 0, 0, 0);                              \
    aB1 = MFMA16(_x11, S##b1, aB1, 0, 0, 0);                              \
  } while (0)

// prologue: set stream pointers, load chunks 0..2 into slots q0..q2
// (always issued AFTER that phase's epi-bias loads -> bias is older, retires
//  at the next loop's first counted wait)
#define B_PROLOGUE(pA, pB) do {                          \
    _wtA = (pA); _wtB = (pB);                            \
    LOAD_SLOT(q0, 0); LOAD_SLOT(q1, 1); LOAD_SLOT(q2, 2);\
  } while (0)

#define ZERO_ACCS do { aA0 = z4; aA1 = z4; aB0 = z4; aB1 = z4; } while (0)

// dist-3 modulo-scheduled loop, 3x unrolled with uniform exits; slot for
// chunk c is c%3; after use it is refilled with chunk c+3.
#define GEMM_LOOP(srcA, SST, ncv) do {                   \
    int _c = 0;                                          \
    for (;;) {                                           \
      WAITSEL(_c, ncv);                                  \
      USE_SLOT(q0, srcA, SST, _c);                       \
      if (_c + 3 < (ncv)) LOAD_SLOT(q0, _c + 3);         \
      if (++_c == (ncv)) break;                          \
      WAITSEL(_c, ncv);                                  \
      USE_SLOT(q1, srcA, SST, _c);                       \
      if (_c + 3 < (ncv)) LOAD_SLOT(q1, _c + 3);         \
      if (++_c == (ncv)) break;                          \
      WAITSEL(_c, ncv);                                  \
      USE_SLOT(q2, srcA, SST, _c);                       \
      if (_c + 3 < (ncv)) LOAD_SLOT(q2, _c + 3);         \
      if (++_c == (ncv)) break;                          \
    }                                                    \
  } while (0)

__global__ __launch_bounds__(1024, 4) void iaf_main(
    const float* __restrict__ mean, const float* __restrict__ logv,
    const float* __restrict__ eps,
    const float* __restrict__ b1, const float* __restrict__ b2,
    const float* __restrict__ b3,
    const f16* __restrict__ ws, float* __restrict__ out)
{
  __shared__ float xbuf[32][XSTR];                // 33.3 KB fp32 master x
  __shared__ __align__(16) f16 buf0[32 * 512];    // 32 KB (A1 uses 16 KB)
  __shared__ __align__(16) f16 buf1[32 * 512];    // 32 KB

  const int tid = threadIdx.x;
  const int wid = tid >> 6;
  const int lane = tid & 63;
  const int lrow = lane & 15;    // MFMA row (A) / col (B,C)
  const int lk8 = lane >> 4;     // MFMA k-chunk / row-group
  const int row0 = blockIdx.x * 32;

  // adjacent pairing: wave w owns tiles {2w, 2w+1} (equal prefix counts).
  const int tA = 2 * wid, tB = 2 * wid + 1;
  const int npA = tA * 16, npB = tB * 16;
  const int nc1 = wid / 4 + 1;    // chunk-pairs, W1
  const int nc23 = wid / 2 + 1;   // chunk-pairs, W2/W3

  // per-thread bias gather indices (loop-invariant)
  const int iA = h_orig(npA + lrow);
  const int iB = h_orig(npB + lrow);

  const f32x4 z4 = {0.f, 0.f, 0.f, 0.f};
  f32x4 aA0, aA1, aB0, aB1;
  const f16 *_wtA, *_wtB;
  f16x8 q0a0, q0a1, q0b0, q0b1;
  f16x8 q1a0, q1a1, q1b0, q1b1;
  f16x8 q2a0, q2a1, q2b0, q2b1;
  float b1vA, b1vB, b2vA, b2vB, b3vA, b3vB;

  // per-phase weight stream bases (per-lane)
  const int o1A = tA * 4096 + lane * 8, o1B = tB * 4096 + lane * 8;   // 8ks*512
  const int o2A = tA * 8192 + lane * 8, o2B = tB * 8192 + lane * 8;   // 16ks*512

  // x0 = mean + exp(0.5*log_var)*eps
  {
    int m = tid >> 5;
    int c0 = (tid & 31) * 8;
    const int g = (row0 + m) * ND + c0;
    #pragma unroll
    for (int i = 0; i < 8; i += 4) {
      f32x4 mu = *(const f32x4*)(mean + g + i);
      f32x4 lv = *(const f32x4*)(logv + g + i);
      f32x4 ep = *(const f32x4*)(eps + g + i);
      f32x4 x;
      #pragma unroll
      for (int q = 0; q < 4; ++q) x[q] = mu[q] + __expf(0.5f * lv[q]) * ep[q];
      *(f32x4*)(&xbuf[m][c0 + i]) = x;
    }
  }

  // startup: W1@t=3 epi-bias first, then W1@t=3 prologue (bias stays oldest)
  GLOADW(b1vA, (b1 + 3 * NH + iA));
  GLOADW(b1vB, (b1 + 3 * NH + iB));
  B_PROLOGUE(ws + W1F_OFF + 3 * (NH * ND) + o1A,
             ws + W1F_OFF + 3 * (NH * ND) + o1B);
  __syncthreads();

  for (int t = NT - 1; t >= 0; --t) {
    // A1[m][k] = fp16(x[m][255-k]) (reversal folded in), stride 512B, swizzled
    {
      int m = tid >> 5;
      int k0 = (tid & 31) * 8;
      f32x4 lo = *(const f32x4*)(&xbuf[m][248 - k0]);
      f32x4 hi = *(const f32x4*)(&xbuf[m][252 - k0]);
      f16x8 pk;
      pk[0] = (f16)hi[3]; pk[1] = (f16)hi[2]; pk[2] = (f16)hi[1]; pk[3] = (f16)hi[0];
      pk[4] = (f16)lo[3]; pk[5] = (f16)lo[2]; pk[6] = (f16)lo[1]; pk[7] = (f16)lo[0];
      int off = m * 512 + k0 * 2;
      *(f16x8*)((char*)buf0 + (off ^ ((m & 7) << 4))) = pk;
    }
    __syncthreads();

    // h1 = relu(x_rev @ W1m + b1)   (sorted cols)
    ZERO_ACCS;
    GEMM_LOOP(buf0, 512, nc1);
    GLOADW(b2vA, (b2 + t * NH + iA));                   // W2 epi-bias (oldest)
    GLOADW(b2vB, (b2 + t * NH + iB));
    B_PROLOGUE(ws + W2F_OFF + t * (NH * NH) + o2A,      // W2 stream, in flight
               ws + W2F_OFF + t * (NH * NH) + o2B);
    epi_relu_tile(aA0, aA1, b1vA, buf1, npA, lrow, lk8);
    epi_relu_tile(aB0, aB1, b1vB, buf1, npB, lrow, lk8);
    __syncthreads();

    // h2 = relu(h1 @ W2m + b2)   (sorted rows+cols)
    ZERO_ACCS;
    GEMM_LOOP(buf1, 1024, nc23);
    GLOADW(b3vA, (b3 + t * (2 * ND) + npA + lrow));     // W3 epi-bias (oldest)
    GLOADW(b3vB, (b3 + t * (2 * ND) + npB + lrow));
    B_PROLOGUE(ws + W3F_OFF + t * (NH * NH) + o2A,      // W3 stream
               ws + W3F_OFF + t * (NH * NH) + o2B);
    epi_relu_tile(aA0, aA1, b2vA, buf0, npA, lrow, lk8);
    epi_relu_tile(aB0, aB1, b2vB, buf0, npB, lrow, lk8);
    __syncthreads();

    // out = h2 @ W3m + b3 ;  shift = out[:,2d], log_var = out[:,2d+1]
    ZERO_ACCS;
    GEMM_LOOP(buf0, 1024, nc23);
    {
      const int tn = (t > 0) ? (t - 1) : 0;             // next step's W1
      GLOADW(b1vA, (b1 + tn * NH + iA));
      GLOADW(b1vB, (b1 + tn * NH + iB));
      B_PROLOGUE(ws + W1F_OFF + tn * (NH * ND) + o1A,
                 ws + W1F_OFF + tn * (NH * ND) + o1B);
    }
    {
      const bool ev = (lrow & 1) == 0;
      float xnA[2][4], xnB[2][4];
      #pragma unroll
      for (int pt = 0; pt < 2; ++pt) {
        f32x4 o_0 = pt ? aB0 : aA0;
        f32x4 o_1 = pt ? aB1 : aA1;
        float (*xn)[4] = pt ? xnB : xnA;
        int n = (pt ? npB : npA) + lrow;
        float bv = pt ? b3vB : b3vA;
        #pragma unroll
        for (int j = 0; j < 4; ++j) {
          float o0 = o_0[j] + bv;
          float o1 = o_1[j] + bv;
          float po0 = __shfl_xor(o0, 1);   // partner column (n^1) value
          float po1 = __shfl_xor(o1, 1);
          if (ev) {                         // even col: o=shift, po=pre-tanh lv
            int d = n >> 1;
            float xc0 = xbuf[lk8 * 4 + j][255 - d];
            float e0 = __expf(2.f * po0);
            float t0 = 1.f - 2.f / (e0 + 1.f);          // tanh(po0)
            xn[0][j] = (xc0 - o0) * __expf(-t0);
            float xc1 = xbuf[16 + lk8 * 4 + j][255 - d];
            float e1 = __expf(2.f * po1);
            float t1 = 1.f - 2.f / (e1 + 1.f);
            xn[1][j] = (xc1 - o1) * __expf(-t1);
          }
        }
      }
      __syncthreads();                      // all xbuf reads done
      if (ev) {
        int dA = (npA + lrow) >> 1;
        int dB = (npB + lrow) >> 1;
        #pragma unroll
        for (int j = 0; j < 4; ++j) {
          xbuf[lk8 * 4 + j][dA]      = xnA[0][j];
          xbuf[16 + lk8 * 4 + j][dA] = xnA[1][j];
          xbuf[lk8 * 4 + j][dB]      = xnB[0][j];
          xbuf[16 + lk8 * 4 + j][dB] = xnB[1][j];
        }
      }
      __syncthreads();
    }
  }

  // store final x (fp32)
  {
    int m = tid >> 5;
    int c0 = (tid & 31) * 8;
    float* op = out + (row0 + m) * ND + c0;
    #pragma unroll
    for (int i = 0; i < 8; i += 4)
      *(f32x4*)(op + i) = *(const f32x4*)(&xbuf[m][c0 + i]);
  }
}

extern "C" void kernel_launch(void* const* d_in, const int* in_sizes, int n_in,
                              void* d_out, int out_size, void* d_ws, size_t ws_size,
                              hipStream_t stream) {
  const float* mean = (const float*)d_in[0];
  const float* logv = (const float*)d_in[1];
  const float* eps  = (const float*)d_in[2];
  const float* W1   = (const float*)d_in[3];
  const float* b1   = (const float*)d_in[4];
  const float* W2   = (const float*)d_in[5];
  const float* b2   = (const float*)d_in[6];
  const float* W3   = (const float*)d_in[7];
  const float* b3   = (const float*)d_in[8];
  f16* ws = (f16*)d_ws;   // needs 5.25 MB

  prep_weights<<<(WS_ELEMS + 255) / 256, 256, 0, stream>>>(W1, W2, W3, ws);
  iaf_main<<<NB / 32, 1024, 0, stream>>>(mean, logv, eps, b1, b2, b3, ws,
                                         (float*)d_out);
}